// Round 1
// baseline (103.282 us; speedup 1.0000x reference)
//
#include <hip/hip_runtime.h>
#include <math.h>

#define NB 4096
#define ND 512
#define K2 1024

typedef __attribute__((ext_vector_type(8))) short bf16x8;
typedef __attribute__((ext_vector_type(4))) float f32x4;

__device__ __forceinline__ float wave_max(float v) {
#pragma unroll
  for (int o = 32; o > 0; o >>= 1) v = fmaxf(v, __shfl_xor(v, o));
  return v;
}
__device__ __forceinline__ float wave_sum(float v) {
#pragma unroll
  for (int o = 32; o > 0; o >>= 1) v += __shfl_xor(v, o);
  return v;
}

// RNE float->bf16
__device__ __forceinline__ unsigned short f2bf(float x) {
  union { float f; unsigned int u; } c; c.f = x;
  unsigned int u = c.u;
  return (unsigned short)((u + 0x7fffu + ((u >> 16) & 1u)) >> 16);
}

// ---------------------------------------------------------------------------
// Kernel 1: build A=[v_mean|v_sigma], B=[t_mean|t_sigma] in bf16 (4096x1024),
// plus exact f32 row square-norms a_sq[i]=Σ v_mean²+Σ v_var (σ²=var), b_sq.
// Blocks 0..4095 -> A side, 4096..8191 -> B side. 256 thr, 2 cols each (f32x2).
// ---------------------------------------------------------------------------
__global__ __launch_bounds__(256) void prep_kernel(
    const float* __restrict__ v_mean, const float* __restrict__ v_var,
    const float* __restrict__ t_mean, const float* __restrict__ t_var,
    unsigned short* __restrict__ Abf, unsigned short* __restrict__ Bbf,
    float* __restrict__ a_sq, float* __restrict__ b_sq) {
  int b = blockIdx.x;
  int side = b >> 12;
  int row = b & (NB - 1);
  const float* mean = side ? t_mean : v_mean;
  const float* var = side ? t_var : v_var;
  unsigned short* dst = side ? Bbf : Abf;
  float* sq = side ? b_sq : a_sq;
  int t = threadIdx.x;
  float2 m2 = *(const float2*)(mean + (size_t)row * ND + 2 * t);
  float2 v2 = *(const float2*)(var + (size_t)row * ND + 2 * t);
  float s0 = sqrtf(v2.x), s1 = sqrtf(v2.y);
  ushort2 pm; pm.x = f2bf(m2.x); pm.y = f2bf(m2.y);
  ushort2 ps; ps.x = f2bf(s0); ps.y = f2bf(s1);
  *(ushort2*)(dst + (size_t)row * K2 + 2 * t) = pm;
  *(ushort2*)(dst + (size_t)row * K2 + ND + 2 * t) = ps;
  float p = m2.x * m2.x + m2.y * m2.y + v2.x + v2.y;
  p = wave_sum(p);
  __shared__ float sm[4];
  if ((t & 63) == 0) sm[t >> 6] = p;
  __syncthreads();
  if (t == 0) sq[row] = (sm[0] + sm[1]) + (sm[2] + sm[3]);
}

// ---------------------------------------------------------------------------
// Kernel 2: bf16 MFMA GEMM (m97 structure): C = A·Bᵀ, 128x128 tile, BK=32,
// 4 waves in 2x2, each wave 64x64 (4x4 frags of 16x16x32).
// Epilogue: logits[i][j] = -temp*(a_sq[i]+b_sq[j]-2*cross).
// ---------------------------------------------------------------------------
__global__ __launch_bounds__(256) void gemm_logits_kernel(
    const unsigned short* __restrict__ Abf, const unsigned short* __restrict__ Bbf,
    const float* __restrict__ a_sq, const float* __restrict__ b_sq,
    const float* __restrict__ log_temp, float* __restrict__ logits) {
  __shared__ unsigned short ldsA[128 * 32];
  __shared__ unsigned short ldsB[128 * 32];
  int gid = blockIdx.x;
  int bm = gid >> 5, bn = gid & 31;
  int brow = bm * 128, bcol = bn * 128;
  int tid = threadIdx.x;
  int lane = tid & 63, wid = tid >> 6;
  int wr = wid >> 1, wc = wid & 1;
  int lr = lane & 15, lk = lane >> 4;
  f32x4 acc[4][4] = {};
  for (int k0 = 0; k0 < K2; k0 += 32) {
    // stage 128x32 bf16 tiles of A and B: 512 chunks of 16B each, 2 iters
#pragma unroll
    for (int it = 0; it < 2; ++it) {
      int c = it * 256 + tid;
      int row = c >> 2, kc = c & 3;
      const unsigned short* ga = Abf + (size_t)(brow + row) * K2 + k0 + kc * 8;
      const unsigned short* gb = Bbf + (size_t)(bcol + row) * K2 + k0 + kc * 8;
      __builtin_amdgcn_global_load_lds(
          (const __attribute__((address_space(1))) unsigned int*)ga,
          (__attribute__((address_space(3))) unsigned int*)((char*)ldsA + c * 16),
          16, 0, 0);
      __builtin_amdgcn_global_load_lds(
          (const __attribute__((address_space(1))) unsigned int*)gb,
          (__attribute__((address_space(3))) unsigned int*)((char*)ldsB + c * 16),
          16, 0, 0);
    }
    __syncthreads();
    bf16x8 afr[4], bfr[4];
#pragma unroll
    for (int m = 0; m < 4; ++m)
      afr[m] = *(const bf16x8*)(ldsA + (wr * 64 + m * 16 + lr) * 32 + lk * 8);
#pragma unroll
    for (int n = 0; n < 4; ++n)
      bfr[n] = *(const bf16x8*)(ldsB + (wc * 64 + n * 16 + lr) * 32 + lk * 8);
#pragma unroll
    for (int m = 0; m < 4; ++m)
#pragma unroll
      for (int n = 0; n < 4; ++n)
        acc[m][n] = __builtin_amdgcn_mfma_f32_16x16x32_bf16(afr[m], bfr[n], acc[m][n], 0, 0, 0);
    __syncthreads();
  }
  float temp = fminf(expf(log_temp[0]), 100.0f);
  // C/D layout (m89-verified): col = lane&15, row = (lane>>4)*4 + reg
#pragma unroll
  for (int m = 0; m < 4; ++m) {
#pragma unroll
    for (int r = 0; r < 4; ++r) {
      int row = brow + wr * 64 + m * 16 + lk * 4 + r;
      float asq = a_sq[row];
#pragma unroll
      for (int n = 0; n < 4; ++n) {
        int col = bcol + wc * 64 + n * 16 + lr;
        logits[(size_t)row * NB + col] = -temp * (asq + b_sq[col] - 2.0f * acc[m][n][r]);
      }
    }
  }
}

// ---------------------------------------------------------------------------
// Kernel 3: row logsumexp. One block per row; 256 thr x 16 f32 in registers.
// hrow[i] = lse_row[i] - logits[i][i];  diag[i] = logits[i][i].
// ---------------------------------------------------------------------------
__global__ __launch_bounds__(256) void row_lse_kernel(
    const float* __restrict__ logits, float* __restrict__ hrow,
    float* __restrict__ diag) {
  int i = blockIdx.x;
  int t = threadIdx.x;
  const float4* rowp = (const float4*)(logits + (size_t)i * NB);
  float4 v[4];
  float lmax = -INFINITY;
#pragma unroll
  for (int q = 0; q < 4; ++q) {
    v[q] = rowp[t + q * 256];
    lmax = fmaxf(lmax, fmaxf(fmaxf(v[q].x, v[q].y), fmaxf(v[q].z, v[q].w)));
  }
  lmax = wave_max(lmax);
  __shared__ float smx[4];
  __shared__ float sms[4];
  if ((t & 63) == 0) smx[t >> 6] = lmax;
  __syncthreads();
  float M = fmaxf(fmaxf(smx[0], smx[1]), fmaxf(smx[2], smx[3]));
  float s = 0.f;
#pragma unroll
  for (int q = 0; q < 4; ++q)
    s += __expf(v[q].x - M) + __expf(v[q].y - M) + __expf(v[q].z - M) + __expf(v[q].w - M);
  s = wave_sum(s);
  if ((t & 63) == 0) sms[t >> 6] = s;
  __syncthreads();
  if (t == 0) {
    float S = (sms[0] + sms[1]) + (sms[2] + sms[3]);
    float dv = logits[(size_t)i * NB + i];
    hrow[i] = M + logf(S) - dv;
    diag[i] = dv;
  }
}

// ---------------------------------------------------------------------------
// Kernel 4: column LSE partials. Grid 256 = 16 col-chunks x 16 row-chunks.
// Each block: 256 cols x 256 rows, online (m,s) per column, float4 coalesced.
// ---------------------------------------------------------------------------
__global__ __launch_bounds__(256) void col_partial_kernel(
    const float* __restrict__ logits, float* __restrict__ pm,
    float* __restrict__ ps) {
  int blk = blockIdx.x;
  int cb = blk & 15, rb = blk >> 4;
  int t = threadIdx.x;
  int c0 = cb * 256 + (t & 63) * 4;
  int r0 = rb * 256 + (t >> 6);
  float4 m = {-INFINITY, -INFINITY, -INFINITY, -INFINITY};
  float4 s = {0.f, 0.f, 0.f, 0.f};
  for (int k = 0; k < 64; ++k) {
    int r = r0 + k * 4;
    float4 x = *(const float4*)(logits + (size_t)r * NB + c0);
    float nm;
    nm = fmaxf(m.x, x.x); s.x = s.x * __expf(m.x - nm) + __expf(x.x - nm); m.x = nm;
    nm = fmaxf(m.y, x.y); s.y = s.y * __expf(m.y - nm) + __expf(x.y - nm); m.y = nm;
    nm = fmaxf(m.z, x.z); s.z = s.z * __expf(m.z - nm) + __expf(x.z - nm); m.z = nm;
    nm = fmaxf(m.w, x.w); s.w = s.w * __expf(m.w - nm) + __expf(x.w - nm); m.w = nm;
  }
  __shared__ float smm[1024];
  __shared__ float sms[1024];
  smm[t * 4 + 0] = m.x; smm[t * 4 + 1] = m.y; smm[t * 4 + 2] = m.z; smm[t * 4 + 3] = m.w;
  sms[t * 4 + 0] = s.x; sms[t * 4 + 1] = s.y; sms[t * 4 + 2] = s.z; sms[t * 4 + 3] = s.w;
  __syncthreads();
  if (t < 64) {
#pragma unroll
    for (int q = 0; q < 4; ++q) {
      float M = smm[t * 4 + q], S = sms[t * 4 + q];
#pragma unroll
      for (int g = 1; g < 4; ++g) {
        float mg = smm[(g * 64 + t) * 4 + q], sg = sms[(g * 64 + t) * 4 + q];
        float nM = fmaxf(M, mg);
        S = S * __expf(M - nM) + sg * __expf(mg - nM);
        M = nM;
      }
      pm[(size_t)rb * NB + cb * 256 + t * 4 + q] = M;
      ps[(size_t)rb * NB + cb * 256 + t * 4 + q] = S;
    }
  }
}

// Kernel 5: combine 16 row-chunk partials per column -> lse_col[c].
__global__ __launch_bounds__(256) void col_combine_kernel(
    const float* __restrict__ pm, const float* __restrict__ ps,
    float* __restrict__ lse_col) {
  int c = blockIdx.x * 256 + threadIdx.x;
  float M = -INFINITY, S = 0.f;
#pragma unroll
  for (int g = 0; g < 16; ++g) {
    float mg = pm[(size_t)g * NB + c], sg = ps[(size_t)g * NB + c];
    float nM = fmaxf(M, mg);
    S = S * __expf(M - nM) + sg * __expf(mg - nM);
    M = nM;
  }
  lse_col[c] = M + logf(S);
}

// Kernel 6: final mean in f64: 0.5*mean(hrow) + 0.5*mean(lse_col - diag).
__global__ __launch_bounds__(256) void final_kernel(
    const float* __restrict__ hrow, const float* __restrict__ lse_col,
    const float* __restrict__ diag, float* __restrict__ out) {
  int t = threadIdx.x;
  double a = 0.0;
  for (int i = t; i < NB; i += 256) {
    a += 0.5 * ((double)hrow[i] + (double)(lse_col[i] - diag[i]));
  }
#pragma unroll
  for (int o = 32; o > 0; o >>= 1) a += __shfl_xor(a, o);
  __shared__ double sd[4];
  if ((t & 63) == 0) sd[t >> 6] = a;
  __syncthreads();
  if (t == 0) out[0] = (float)(((sd[0] + sd[1]) + (sd[2] + sd[3])) / (double)NB);
}

extern "C" void kernel_launch(void* const* d_in, const int* in_sizes, int n_in,
                              void* d_out, int out_size, void* d_ws, size_t ws_size,
                              hipStream_t stream) {
  const float* v_mean = (const float*)d_in[0];
  const float* v_var = (const float*)d_in[1];
  const float* t_mean = (const float*)d_in[2];
  const float* t_var = (const float*)d_in[3];
  const float* log_temp = (const float*)d_in[4];
  float* out = (float*)d_out;

  char* ws = (char*)d_ws;
  // workspace layout (~80.6 MiB total)
  float* logits = (float*)ws;                                   // 4096*4096*4 = 64 MiB
  unsigned short* Abf = (unsigned short*)(ws + 67108864);       // 8 MiB
  unsigned short* Bbf = (unsigned short*)(ws + 67108864 + 8388608); // 8 MiB
  float* a_sq = (float*)(ws + 83886080);                        // 16 KiB
  float* b_sq = a_sq + NB;
  float* hrow = b_sq + NB;
  float* diag = hrow + NB;
  float* lse_col = diag + NB;
  float* pm = lse_col + NB;                                     // 16*4096 f32
  float* ps = pm + 16 * NB;                                     // 16*4096 f32

  prep_kernel<<<8192, 256, 0, stream>>>(v_mean, v_var, t_mean, t_var, Abf, Bbf, a_sq, b_sq);
  gemm_logits_kernel<<<1024, 256, 0, stream>>>(Abf, Bbf, a_sq, b_sq, log_temp, logits);
  row_lse_kernel<<<4096, 256, 0, stream>>>(logits, hrow, diag);
  col_partial_kernel<<<256, 256, 0, stream>>>(logits, pm, ps);
  col_combine_kernel<<<16, 256, 0, stream>>>(pm, ps, lse_col);
  final_kernel<<<1, 256, 0, stream>>>(hrow, lse_col, diag, out);
}

// Round 2
// 80.797 us; speedup vs baseline: 1.2783x; 1.2783x over previous
//
#include <hip/hip_runtime.h>
#include <math.h>

#define NB 4096
#define ND 512
#define K2 1024

typedef __attribute__((ext_vector_type(8))) short bf16x8;
typedef __attribute__((ext_vector_type(4))) float f32x4;

__device__ __forceinline__ float wave_sum(float v) {
#pragma unroll
  for (int o = 32; o > 0; o >>= 1) v += __shfl_xor(v, o);
  return v;
}

// RNE float->bf16
__device__ __forceinline__ unsigned short f2bf(float x) {
  union { float f; unsigned int u; } c; c.f = x;
  unsigned int u = c.u;
  return (unsigned short)((u + 0x7fffu + ((u >> 16) & 1u)) >> 16);
}

// ---------------------------------------------------------------------------
// Kernel 1: build A=[v_mean|v_sigma], B=[t_mean|t_sigma] in bf16 (4096x1024),
// plus exact f32 row square-norms a_sq[i]=Σ mean² + Σ var (σ²=var).
// Blocks 0..4095 -> A side, 4096..8191 -> B side. 256 thr, 2 cols each.
// ---------------------------------------------------------------------------
__global__ __launch_bounds__(256) void prep_kernel(
    const float* __restrict__ v_mean, const float* __restrict__ v_var,
    const float* __restrict__ t_mean, const float* __restrict__ t_var,
    unsigned short* __restrict__ Abf, unsigned short* __restrict__ Bbf,
    float* __restrict__ a_sq, float* __restrict__ b_sq) {
  int b = blockIdx.x;
  int side = b >> 12;
  int row = b & (NB - 1);
  const float* mean = side ? t_mean : v_mean;
  const float* var = side ? t_var : v_var;
  unsigned short* dst = side ? Bbf : Abf;
  float* sq = side ? b_sq : a_sq;
  int t = threadIdx.x;
  float2 m2 = *(const float2*)(mean + (size_t)row * ND + 2 * t);
  float2 v2 = *(const float2*)(var + (size_t)row * ND + 2 * t);
  float s0 = sqrtf(v2.x), s1 = sqrtf(v2.y);
  ushort2 pm; pm.x = f2bf(m2.x); pm.y = f2bf(m2.y);
  ushort2 ps; ps.x = f2bf(s0); ps.y = f2bf(s1);
  *(ushort2*)(dst + (size_t)row * K2 + 2 * t) = pm;
  *(ushort2*)(dst + (size_t)row * K2 + ND + 2 * t) = ps;
  float p = m2.x * m2.x + m2.y * m2.y + v2.x + v2.y;
  p = wave_sum(p);
  __shared__ float sm[4];
  if ((t & 63) == 0) sm[t >> 6] = p;
  __syncthreads();
  if (t == 0) sq[row] = (sm[0] + sm[1]) + (sm[2] + sm[3]);
}

// ---------------------------------------------------------------------------
// Kernel 2: bf16 MFMA GEMM (m97 structure) with FUSED online-LSE partials.
// C = A·Bᵀ, 128x128 tile, BK=32, 4 waves 2x2, each wave 64x64 (4x4 frags).
// Epilogue: logits in-place in acc, then per-wave (M,S) partials:
//   rowM/rowS[row][chunk]  chunk = bn*2+wc   (64-col chunks)
//   colM/colS[col][chunk]  chunk = bm*2+wr   (64-row chunks)
// Diagonal blocks also write diag[i].
// ---------------------------------------------------------------------------
__global__ __launch_bounds__(256) void gemm_fused_kernel(
    const unsigned short* __restrict__ Abf, const unsigned short* __restrict__ Bbf,
    const float* __restrict__ a_sq, const float* __restrict__ b_sq,
    const float* __restrict__ log_temp,
    float* __restrict__ rowM, float* __restrict__ rowS,
    float* __restrict__ colM, float* __restrict__ colS,
    float* __restrict__ diag) {
  __shared__ unsigned short ldsA[128 * 32];
  __shared__ unsigned short ldsB[128 * 32];
  int gid = blockIdx.x;
  int bm = gid >> 5, bn = gid & 31;
  int brow = bm * 128, bcol = bn * 128;
  int tid = threadIdx.x;
  int lane = tid & 63, wid = tid >> 6;
  int wr = wid >> 1, wc = wid & 1;
  int lr = lane & 15, lk = lane >> 4;
  f32x4 acc[4][4] = {};
  for (int k0 = 0; k0 < K2; k0 += 32) {
#pragma unroll
    for (int it = 0; it < 2; ++it) {
      int c = it * 256 + tid;
      int row = c >> 2, kc = c & 3;
      const unsigned short* ga = Abf + (size_t)(brow + row) * K2 + k0 + kc * 8;
      const unsigned short* gb = Bbf + (size_t)(bcol + row) * K2 + k0 + kc * 8;
      __builtin_amdgcn_global_load_lds(
          (const __attribute__((address_space(1))) unsigned int*)ga,
          (__attribute__((address_space(3))) unsigned int*)((char*)ldsA + c * 16),
          16, 0, 0);
      __builtin_amdgcn_global_load_lds(
          (const __attribute__((address_space(1))) unsigned int*)gb,
          (__attribute__((address_space(3))) unsigned int*)((char*)ldsB + c * 16),
          16, 0, 0);
    }
    __syncthreads();
    bf16x8 afr[4], bfr[4];
#pragma unroll
    for (int m = 0; m < 4; ++m)
      afr[m] = *(const bf16x8*)(ldsA + (wr * 64 + m * 16 + lr) * 32 + lk * 8);
#pragma unroll
    for (int n = 0; n < 4; ++n)
      bfr[n] = *(const bf16x8*)(ldsB + (wc * 64 + n * 16 + lr) * 32 + lk * 8);
#pragma unroll
    for (int m = 0; m < 4; ++m)
#pragma unroll
      for (int n = 0; n < 4; ++n)
        acc[m][n] = __builtin_amdgcn_mfma_f32_16x16x32_bf16(afr[m], bfr[n], acc[m][n], 0, 0, 0);
    __syncthreads();
  }
  float temp = fminf(expf(log_temp[0]), 100.0f);
  // In-place: acc[m][n][r] -> logit. C/D layout: col=lane&15, row=(lane>>4)*4+reg
#pragma unroll
  for (int m = 0; m < 4; ++m) {
#pragma unroll
    for (int r = 0; r < 4; ++r) {
      float asq = a_sq[brow + wr * 64 + m * 16 + lk * 4 + r];
#pragma unroll
      for (int n = 0; n < 4; ++n) {
        float bsq = b_sq[bcol + wc * 64 + n * 16 + lr];
        acc[m][n][r] = -temp * (asq + bsq - 2.0f * acc[m][n][r]);
      }
    }
  }
  // Diagonal extraction
  if (bm == bn) {
#pragma unroll
    for (int m = 0; m < 4; ++m)
#pragma unroll
      for (int n = 0; n < 4; ++n)
#pragma unroll
        for (int r = 0; r < 4; ++r) {
          int rl = wr * 64 + m * 16 + lk * 4 + r;
          int cl = wc * 64 + n * 16 + lr;
          if (rl == cl) diag[brow + rl] = acc[m][n][r];
        }
  }
  // Row partials: per (m,r) reduce over n (in-lane) and lr (16 lanes, same lk)
#pragma unroll
  for (int m = 0; m < 4; ++m) {
#pragma unroll
    for (int r = 0; r < 4; ++r) {
      float mx = fmaxf(fmaxf(acc[m][0][r], acc[m][1][r]),
                       fmaxf(acc[m][2][r], acc[m][3][r]));
#pragma unroll
      for (int o = 1; o < 16; o <<= 1) mx = fmaxf(mx, __shfl_xor(mx, o));
      float s = __expf(acc[m][0][r] - mx) + __expf(acc[m][1][r] - mx) +
                __expf(acc[m][2][r] - mx) + __expf(acc[m][3][r] - mx);
#pragma unroll
      for (int o = 1; o < 16; o <<= 1) s += __shfl_xor(s, o);
      if (lr == 0) {
        int row = brow + wr * 64 + m * 16 + lk * 4 + r;
        int ch = bn * 2 + wc;
        rowM[(size_t)row * 64 + ch] = mx;
        rowS[(size_t)row * 64 + ch] = s;
      }
    }
  }
  // Col partials: per n reduce over (m,r) in-lane and lk (4 groups)
#pragma unroll
  for (int n = 0; n < 4; ++n) {
    float mx = -INFINITY;
#pragma unroll
    for (int m = 0; m < 4; ++m)
#pragma unroll
      for (int r = 0; r < 4; ++r) mx = fmaxf(mx, acc[m][n][r]);
    mx = fmaxf(mx, __shfl_xor(mx, 16));
    mx = fmaxf(mx, __shfl_xor(mx, 32));
    float s = 0.f;
#pragma unroll
    for (int m = 0; m < 4; ++m)
#pragma unroll
      for (int r = 0; r < 4; ++r) s += __expf(acc[m][n][r] - mx);
    s += __shfl_xor(s, 16);
    s += __shfl_xor(s, 32);
    if (lk == 0) {
      int col = bcol + wc * 64 + n * 16 + lr;
      int ch = bm * 2 + wr;
      colM[(size_t)col * 64 + ch] = mx;
      colS[(size_t)col * 64 + ch] = s;
    }
  }
}

// ---------------------------------------------------------------------------
// Kernel 3: combine 64 chunk-partials per row/col -> (lse - diag).
// Grid 2048 x 256 thr (4 waves). Blocks 0..1023: rows, 1024..2047: cols.
// One wave per row/col: lane l holds chunk l, butterfly online-merge.
// ---------------------------------------------------------------------------
__global__ __launch_bounds__(256) void combine_kernel(
    const float* __restrict__ rowM, const float* __restrict__ rowS,
    const float* __restrict__ colM, const float* __restrict__ colS,
    const float* __restrict__ diag, float* __restrict__ hrow,
    float* __restrict__ hcol) {
  int b = blockIdx.x;
  int t = threadIdx.x;
  int wave = t >> 6, lane = t & 63;
  int isCol = b >> 10;
  int idx = (b & 1023) * 4 + wave;
  const float* PM = isCol ? colM : rowM;
  const float* PS = isCol ? colS : rowS;
  float M = PM[(size_t)idx * 64 + lane];
  float S = PS[(size_t)idx * 64 + lane];
#pragma unroll
  for (int o = 1; o < 64; o <<= 1) {
    float M2 = __shfl_xor(M, o), S2 = __shfl_xor(S, o);
    float nM = fmaxf(M, M2);
    S = S * __expf(M - nM) + S2 * __expf(M2 - nM);
    M = nM;
  }
  if (lane == 0) {
    float v = M + logf(S) - diag[idx];
    (isCol ? hcol : hrow)[idx] = v;
  }
}

// Kernel 4: final mean in f64: 0.5*(mean(hrow) + mean(hcol)).
__global__ __launch_bounds__(256) void final_kernel(
    const float* __restrict__ hrow, const float* __restrict__ hcol,
    float* __restrict__ out) {
  int t = threadIdx.x;
  double a = 0.0;
  for (int i = t; i < NB; i += 256) {
    a += 0.5 * ((double)hrow[i] + (double)hcol[i]);
  }
#pragma unroll
  for (int o = 32; o > 0; o >>= 1) a += __shfl_xor(a, o);
  __shared__ double sd[4];
  if ((t & 63) == 0) sd[t >> 6] = a;
  __syncthreads();
  if (t == 0) out[0] = (float)(((sd[0] + sd[1]) + (sd[2] + sd[3])) / (double)NB);
}

extern "C" void kernel_launch(void* const* d_in, const int* in_sizes, int n_in,
                              void* d_out, int out_size, void* d_ws, size_t ws_size,
                              hipStream_t stream) {
  const float* v_mean = (const float*)d_in[0];
  const float* v_var = (const float*)d_in[1];
  const float* t_mean = (const float*)d_in[2];
  const float* t_var = (const float*)d_in[3];
  const float* log_temp = (const float*)d_in[4];
  float* out = (float*)d_out;

  char* ws = (char*)d_ws;
  // workspace layout (~20.4 MiB total)
  unsigned short* Abf = (unsigned short*)ws;                     // 8 MiB
  unsigned short* Bbf = (unsigned short*)(ws + 8388608);         // 8 MiB
  float* rowM = (float*)(ws + 16777216);                         // 1 MiB each
  float* rowS = rowM + (size_t)NB * 64;
  float* colM = rowS + (size_t)NB * 64;
  float* colS = colM + (size_t)NB * 64;
  float* diag = colS + (size_t)NB * 64;                          // 16 KiB
  float* hrow = diag + NB;
  float* hcol = hrow + NB;
  float* a_sq = hcol + NB;
  float* b_sq = a_sq + NB;

  prep_kernel<<<8192, 256, 0, stream>>>(v_mean, v_var, t_mean, t_var, Abf, Bbf, a_sq, b_sq);
  gemm_fused_kernel<<<1024, 256, 0, stream>>>(Abf, Bbf, a_sq, b_sq, log_temp,
                                              rowM, rowS, colM, colS, diag);
  combine_kernel<<<2048, 256, 0, stream>>>(rowM, rowS, colM, colS, diag, hrow, hcol);
  final_kernel<<<1, 256, 0, stream>>>(hrow, hcol, out);
}

// Round 3
// 67.232 us; speedup vs baseline: 1.5362x; 1.2018x over previous
//
#include <hip/hip_runtime.h>
#include <math.h>

#define NB 4096
#define ND 512
#define K2 1024
#define NT 16  // K2 / 64 K-tiles

typedef __attribute__((ext_vector_type(8))) short bf16x8;
typedef __attribute__((ext_vector_type(4))) float f32x4;

__device__ __forceinline__ float wave_sum(float v) {
#pragma unroll
  for (int o = 32; o > 0; o >>= 1) v += __shfl_xor(v, o);
  return v;
}

// RNE float->bf16
__device__ __forceinline__ unsigned short f2bf(float x) {
  union { float f; unsigned int u; } c; c.f = x;
  unsigned int u = c.u;
  return (unsigned short)((u + 0x7fffu + ((u >> 16) & 1u)) >> 16);
}

// ---------------------------------------------------------------------------
// Kernel 1: build A=[v_mean|v_sigma], B=[t_mean|t_sigma] in bf16 (4096x1024),
// plus exact f32 row square-norms a_sq[i]=Σ mean² + Σ var (σ²=var).
// ---------------------------------------------------------------------------
__global__ __launch_bounds__(256) void prep_kernel(
    const float* __restrict__ v_mean, const float* __restrict__ v_var,
    const float* __restrict__ t_mean, const float* __restrict__ t_var,
    unsigned short* __restrict__ Abf, unsigned short* __restrict__ Bbf,
    float* __restrict__ a_sq, float* __restrict__ b_sq) {
  int b = blockIdx.x;
  int side = b >> 12;
  int row = b & (NB - 1);
  const float* mean = side ? t_mean : v_mean;
  const float* var = side ? t_var : v_var;
  unsigned short* dst = side ? Bbf : Abf;
  float* sq = side ? b_sq : a_sq;
  int t = threadIdx.x;
  float2 m2 = *(const float2*)(mean + (size_t)row * ND + 2 * t);
  float2 v2 = *(const float2*)(var + (size_t)row * ND + 2 * t);
  float s0 = sqrtf(v2.x), s1 = sqrtf(v2.y);
  ushort2 pm; pm.x = f2bf(m2.x); pm.y = f2bf(m2.y);
  ushort2 ps; ps.x = f2bf(s0); ps.y = f2bf(s1);
  *(ushort2*)(dst + (size_t)row * K2 + 2 * t) = pm;
  *(ushort2*)(dst + (size_t)row * K2 + ND + 2 * t) = ps;
  float p = m2.x * m2.x + m2.y * m2.y + v2.x + v2.y;
  p = wave_sum(p);
  __shared__ float sm[4];
  if ((t & 63) == 0) sm[t >> 6] = p;
  __syncthreads();
  if (t == 0) sq[row] = (sm[0] + sm[1]) + (sm[2] + sm[3]);
}

// ---------------------------------------------------------------------------
// Stage one 256x64 bf16 tile (32 KB) into linear LDS via global_load_lds x4,
// with the T2 read-swizzle pre-applied on the GLOBAL source address (rule #21:
// linear dest + inverse-swizzled source + swizzled read; XOR is an involution).
// Physical LDS slot (r, q) holds global bytes (r, q ^ ((r&7)<<4)).
// ---------------------------------------------------------------------------
__device__ __forceinline__ void stage_tile(const unsigned short* __restrict__ G,
                                           int grow0, int k0,
                                           unsigned short* lbuf, int tid) {
#pragma unroll
  for (int s = 0; s < 4; ++s) {
    int r = s * 64 + (tid >> 3);
    int q = (tid & 7) * 16;                 // byte offset within 128B row
    int src_b = q ^ ((r & 7) << 4);         // inverse-swizzled source byte
    const unsigned short* ga = G + (size_t)(grow0 + r) * K2 + k0 + (src_b >> 1);
    __builtin_amdgcn_global_load_lds(
        (const __attribute__((address_space(1))) unsigned int*)ga,
        (__attribute__((address_space(3))) unsigned int*)((char*)lbuf + s * 8192 + tid * 16),
        16, 0, 0);
  }
}

// Swizzled fragment read: logical (row, kbyte) -> physical row*128 + (kb ^ sw).
__device__ __forceinline__ bf16x8 lds_frag(const unsigned short* buf, int row, int kb) {
  return *(const bf16x8*)((const char*)buf + row * 128 + (kb ^ ((row & 7) << 4)));
}

// ---------------------------------------------------------------------------
// Kernel 2: 256x256-tile bf16 MFMA GEMM, BK=64, 8 waves (2Mx4N), double-buffered
// LDS (128 KiB), counted-vmcnt pipeline, fused online-LSE partials.
// Per wave: 128x64 output = acc[8][4] f32x4. Per K-tile: 4 phases x 16 MFMA.
//   rowM/rowS[row][64]  chunk = bn*4+wc          (64-col chunks)
//   colM/colS[col][64]  chunk = bm*4+wr*2+(lk>>1) (64-row chunks, interleaved)
// ---------------------------------------------------------------------------
__global__ __launch_bounds__(512) void gemm_fused_kernel(
    const unsigned short* __restrict__ Abf, const unsigned short* __restrict__ Bbf,
    const float* __restrict__ a_sq, const float* __restrict__ b_sq,
    const float* __restrict__ log_temp,
    float* __restrict__ rowM, float* __restrict__ rowS,
    float* __restrict__ colM, float* __restrict__ colS,
    float* __restrict__ diag) {
  __shared__ unsigned short ldsA[2][256 * 64];
  __shared__ unsigned short ldsB[2][256 * 64];
  int bid = blockIdx.x;
  // XCD-aware swizzle: 256 blocks, 8 XCDs -> 32 contiguous per XCD (bijective).
  int swz = (bid & 7) * 32 + (bid >> 3);
  int bm = swz >> 4, bn = swz & 15;
  int brow = bm * 256, bcol = bn * 256;
  int tid = threadIdx.x;
  int lane = tid & 63, wid = tid >> 6;
  int wr = wid >> 2, wc = wid & 3;  // 2x4 wave grid
  int lr = lane & 15, lk = lane >> 4;

  f32x4 acc[8][4] = {};

  // Prologue: stage tiles 0,1; wait tile 0 (8 of 16 loads), sync.
  stage_tile(Abf, brow, 0, ldsA[0], tid);
  stage_tile(Bbf, bcol, 0, ldsB[0], tid);
  stage_tile(Abf, brow, 64, ldsA[1], tid);
  stage_tile(Bbf, bcol, 64, ldsB[1], tid);
  asm volatile("s_waitcnt vmcnt(8)" ::: "memory");
  __builtin_amdgcn_s_barrier();

  for (int t = 0; t < NT; ++t) {
    const int c = t & 1;
    const unsigned short* bufa = ldsA[c];
    const unsigned short* bufb = ldsB[c];
    bf16x8 af[4][2], bf0[2][2], bf1[2][2];
    // --- phase 1: read A(mh=0) + B(nh=0); MFMA m0..3 x n0..1 ---
#pragma unroll
    for (int mi = 0; mi < 4; ++mi)
#pragma unroll
      for (int ks = 0; ks < 2; ++ks)
        af[mi][ks] = lds_frag(bufa, wr * 128 + mi * 16 + lr, ks * 64 + lk * 16);
#pragma unroll
    for (int ni = 0; ni < 2; ++ni)
#pragma unroll
      for (int ks = 0; ks < 2; ++ks)
        bf0[ni][ks] = lds_frag(bufb, wc * 64 + ni * 16 + lr, ks * 64 + lk * 16);
    __builtin_amdgcn_s_setprio(1);
#pragma unroll
    for (int mi = 0; mi < 4; ++mi)
#pragma unroll
      for (int ni = 0; ni < 2; ++ni)
#pragma unroll
        for (int ks = 0; ks < 2; ++ks)
          acc[mi][ni] = __builtin_amdgcn_mfma_f32_16x16x32_bf16(af[mi][ks], bf0[ni][ks], acc[mi][ni], 0, 0, 0);
    __builtin_amdgcn_s_setprio(0);
    __builtin_amdgcn_sched_barrier(0);
    // --- phase 2: read B(nh=1); MFMA m0..3 x n2..3 ---
#pragma unroll
    for (int ni = 0; ni < 2; ++ni)
#pragma unroll
      for (int ks = 0; ks < 2; ++ks)
        bf1[ni][ks] = lds_frag(bufb, wc * 64 + 32 + ni * 16 + lr, ks * 64 + lk * 16);
    __builtin_amdgcn_s_setprio(1);
#pragma unroll
    for (int mi = 0; mi < 4; ++mi)
#pragma unroll
      for (int ni = 0; ni < 2; ++ni)
#pragma unroll
        for (int ks = 0; ks < 2; ++ks)
          acc[mi][2 + ni] = __builtin_amdgcn_mfma_f32_16x16x32_bf16(af[mi][ks], bf1[ni][ks], acc[mi][2 + ni], 0, 0, 0);
    __builtin_amdgcn_s_setprio(0);
    __builtin_amdgcn_sched_barrier(0);
    // --- phase 3: read A(mh=1); MFMA m4..7 x n0..1 ---
#pragma unroll
    for (int mi = 0; mi < 4; ++mi)
#pragma unroll
      for (int ks = 0; ks < 2; ++ks)
        af[mi][ks] = lds_frag(bufa, wr * 128 + 64 + mi * 16 + lr, ks * 64 + lk * 16);
    __builtin_amdgcn_s_setprio(1);
#pragma unroll
    for (int mi = 0; mi < 4; ++mi)
#pragma unroll
      for (int ni = 0; ni < 2; ++ni)
#pragma unroll
        for (int ks = 0; ks < 2; ++ks)
          acc[4 + mi][ni] = __builtin_amdgcn_mfma_f32_16x16x32_bf16(af[mi][ks], bf0[ni][ks], acc[4 + mi][ni], 0, 0, 0);
    __builtin_amdgcn_s_setprio(0);
    __builtin_amdgcn_sched_barrier(0);
    // All buf[c] ds_reads issued & drained -> safe to restage buf[c].
    asm volatile("s_waitcnt lgkmcnt(0)" ::: "memory");
    __builtin_amdgcn_sched_barrier(0);
    __builtin_amdgcn_s_barrier();  // barrier-1
    if (t + 2 < NT) {
      stage_tile(Abf, brow, (t + 2) * 64, ldsA[c], tid);
      stage_tile(Bbf, bcol, (t + 2) * 64, ldsB[c], tid);
    }
    __builtin_amdgcn_sched_barrier(0);
    // --- phase 4: MFMA m4..7 x n2..3 (register-only, overlaps stage issue) ---
    __builtin_amdgcn_s_setprio(1);
#pragma unroll
    for (int mi = 0; mi < 4; ++mi)
#pragma unroll
      for (int ni = 0; ni < 2; ++ni)
#pragma unroll
        for (int ks = 0; ks < 2; ++ks)
          acc[4 + mi][2 + ni] = __builtin_amdgcn_mfma_f32_16x16x32_bf16(af[mi][ks], bf1[ni][ks], acc[4 + mi][2 + ni], 0, 0, 0);
    __builtin_amdgcn_s_setprio(0);
    __builtin_amdgcn_sched_barrier(0);
    // Counted wait: tile t+1 (next-read) landed; tile t+2's 8 loads stay in flight.
    if (t < NT - 2) {
      asm volatile("s_waitcnt vmcnt(8)" ::: "memory");
    } else {
      asm volatile("s_waitcnt vmcnt(0)" ::: "memory");
    }
    __builtin_amdgcn_s_barrier();  // barrier-2
  }

  // ---- epilogue: logits in-place, diag, fused online-LSE partials ----
  float temp = fminf(expf(log_temp[0]), 100.0f);
#pragma unroll
  for (int m = 0; m < 8; ++m) {
#pragma unroll
    for (int r = 0; r < 4; ++r) {
      float asq = a_sq[brow + wr * 128 + m * 16 + lk * 4 + r];
#pragma unroll
      for (int n = 0; n < 4; ++n) {
        float bsq = b_sq[bcol + wc * 64 + n * 16 + lr];
        acc[m][n][r] = -temp * (asq + bsq - 2.0f * acc[m][n][r]);
      }
    }
  }
  if (bm == bn) {
#pragma unroll
    for (int m = 0; m < 8; ++m)
#pragma unroll
      for (int n = 0; n < 4; ++n)
#pragma unroll
        for (int r = 0; r < 4; ++r) {
          int rl = wr * 128 + m * 16 + lk * 4 + r;
          int cl = wc * 64 + n * 16 + lr;
          if (rl == cl) diag[brow + rl] = acc[m][n][r];
        }
  }
  // Row partials: per (m,r): 4 in-lane + reduce across lr (16 lanes).
#pragma unroll
  for (int m = 0; m < 8; ++m) {
#pragma unroll
    for (int r = 0; r < 4; ++r) {
      float mx = fmaxf(fmaxf(acc[m][0][r], acc[m][1][r]),
                       fmaxf(acc[m][2][r], acc[m][3][r]));
#pragma unroll
      for (int o = 1; o < 16; o <<= 1) mx = fmaxf(mx, __shfl_xor(mx, o));
      float s = __expf(acc[m][0][r] - mx) + __expf(acc[m][1][r] - mx) +
                __expf(acc[m][2][r] - mx) + __expf(acc[m][3][r] - mx);
#pragma unroll
      for (int o = 1; o < 16; o <<= 1) s += __shfl_xor(s, o);
      if (lr == 0) {
        int row = brow + wr * 128 + m * 16 + lk * 4 + r;
        int ch = bn * 4 + wc;
        rowM[(size_t)row * 64 + ch] = mx;
        rowS[(size_t)row * 64 + ch] = s;
      }
    }
  }
  // Col partials: per n: 32 in-lane (m,r) + merge lk with lk^1 (xor 16).
#pragma unroll
  for (int n = 0; n < 4; ++n) {
    float mx = -INFINITY;
#pragma unroll
    for (int m = 0; m < 8; ++m)
#pragma unroll
      for (int r = 0; r < 4; ++r) mx = fmaxf(mx, acc[m][n][r]);
    mx = fmaxf(mx, __shfl_xor(mx, 16));
    float s = 0.f;
#pragma unroll
    for (int m = 0; m < 8; ++m)
#pragma unroll
      for (int r = 0; r < 4; ++r) s += __expf(acc[m][n][r] - mx);
    // note: mx is already the pair-merged max, so the two partial sums add directly
    s += __shfl_xor(s, 16);
    if ((lk & 1) == 0) {
      int col = bcol + wc * 64 + n * 16 + lr;
      int ch = bm * 4 + wr * 2 + (lk >> 1);
      colM[(size_t)col * 64 + ch] = mx;
      colS[(size_t)col * 64 + ch] = s;
    }
  }
}

// ---------------------------------------------------------------------------
// Kernel 3: combine 64 chunk-partials per row/col -> (lse - diag).
// ---------------------------------------------------------------------------
__global__ __launch_bounds__(256) void combine_kernel(
    const float* __restrict__ rowM, const float* __restrict__ rowS,
    const float* __restrict__ colM, const float* __restrict__ colS,
    const float* __restrict__ diag, float* __restrict__ hrow,
    float* __restrict__ hcol) {
  int b = blockIdx.x;
  int t = threadIdx.x;
  int wave = t >> 6, lane = t & 63;
  int isCol = b >> 10;
  int idx = (b & 1023) * 4 + wave;
  const float* PM = isCol ? colM : rowM;
  const float* PS = isCol ? colS : rowS;
  float M = PM[(size_t)idx * 64 + lane];
  float S = PS[(size_t)idx * 64 + lane];
#pragma unroll
  for (int o = 1; o < 64; o <<= 1) {
    float M2 = __shfl_xor(M, o), S2 = __shfl_xor(S, o);
    float nM = fmaxf(M, M2);
    S = S * __expf(M - nM) + S2 * __expf(M2 - nM);
    M = nM;
  }
  if (lane == 0) {
    float v = M + logf(S) - diag[idx];
    (isCol ? hcol : hrow)[idx] = v;
  }
}

// Kernel 4: final mean in f64: 0.5*(mean(hrow) + mean(hcol)).
__global__ __launch_bounds__(256) void final_kernel(
    const float* __restrict__ hrow, const float* __restrict__ hcol,
    float* __restrict__ out) {
  int t = threadIdx.x;
  double a = 0.0;
  for (int i = t; i < NB; i += 256) {
    a += 0.5 * ((double)hrow[i] + (double)hcol[i]);
  }
#pragma unroll
  for (int o = 32; o > 0; o >>= 1) a += __shfl_xor(a, o);
  __shared__ double sd[4];
  if ((t & 63) == 0) sd[t >> 6] = a;
  __syncthreads();
  if (t == 0) out[0] = (float)(((sd[0] + sd[1]) + (sd[2] + sd[3])) / (double)NB);
}

extern "C" void kernel_launch(void* const* d_in, const int* in_sizes, int n_in,
                              void* d_out, int out_size, void* d_ws, size_t ws_size,
                              hipStream_t stream) {
  const float* v_mean = (const float*)d_in[0];
  const float* v_var = (const float*)d_in[1];
  const float* t_mean = (const float*)d_in[2];
  const float* t_var = (const float*)d_in[3];
  const float* log_temp = (const float*)d_in[4];
  float* out = (float*)d_out;

  char* ws = (char*)d_ws;
  unsigned short* Abf = (unsigned short*)ws;                     // 8 MiB
  unsigned short* Bbf = (unsigned short*)(ws + 8388608);         // 8 MiB
  float* rowM = (float*)(ws + 16777216);                         // 1 MiB each
  float* rowS = rowM + (size_t)NB * 64;
  float* colM = rowS + (size_t)NB * 64;
  float* colS = colM + (size_t)NB * 64;
  float* diag = colS + (size_t)NB * 64;                          // 16 KiB each
  float* hrow = diag + NB;
  float* hcol = hrow + NB;
  float* a_sq = hcol + NB;
  float* b_sq = a_sq + NB;

  prep_kernel<<<8192, 256, 0, stream>>>(v_mean, v_var, t_mean, t_var, Abf, Bbf, a_sq, b_sq);
  gemm_fused_kernel<<<256, 512, 0, stream>>>(Abf, Bbf, a_sq, b_sq, log_temp,
                                             rowM, rowS, colM, colS, diag);
  combine_kernel<<<2048, 256, 0, stream>>>(rowM, rowS, colM, colS, diag, hrow, hcol);
  final_kernel<<<1, 256, 0, stream>>>(hrow, hcol, out);
}